// Round 15
// baseline (71.466 us; speedup 1.0000x reference)
//
#include <hip/hip_runtime.h>

#define NIN   784
#define NOUT  512
#define NROWS 785      // NIN + 1 (bias row)
#define BATCH 256
#define CHUNK 16       // i-rows per staged tile
#define KCH   2        // chunks per block (sequential, acc in registers)
#define NZ    25       // 25 * 32 = 800 >= 785 (pad rows contribute 0)

static constexpr float G_MIN_F  = (float)(1.0 / 983.3);
static constexpr float G_DIFF_F = (float)(1.0 / 281.3 - 1.0 / 983.3);

// device fast transcendental: v_log_f32 (log2), v_exp_f32 (2^x)
__device__ __forceinline__ float dlog2(float v) { return __builtin_amdgcn_logf(v); }
__device__ __forceinline__ float dexp2(float v) { return __builtin_amdgcn_exp2f(v); }

// 256-thread-block reduce of the 128 partial maxima (all threads return max).
__device__ __forceinline__ float load_maxw(const float* __restrict__ pm, int tid) {
    float m = pm[tid & 127];
    #pragma unroll
    for (int off = 1; off < 64; off <<= 1)
        m = fmaxf(m, __shfl_xor(m, off, 64));
    __shared__ float sm2[4];
    if ((tid & 63) == 0) sm2[tid >> 6] = m;
    __syncthreads();
    return fmaxf(fmaxf(sm2[0], sm2[1]), fmaxf(sm2[2], sm2[3]));
}

// ---------------------------------------------------------------------------
// Kernel 1: per-block partial max over |weights| (vectorized) + zero d_out.
// 128 blocks x 256 threads; 32768 float4 = exactly one per thread.
// ---------------------------------------------------------------------------
__global__ __launch_bounds__(256) void mk_max(
    const float* __restrict__ wp, const float* __restrict__ wn,
    const float* __restrict__ bp, const float* __restrict__ bn,
    float* __restrict__ part, float4* __restrict__ out4)
{
    const int gid = blockIdx.x * 256 + threadIdx.x;
    out4[gid] = make_float4(0.f, 0.f, 0.f, 0.f);

    float m = 0.0f;
    const int n4 = NIN * NOUT / 4;
    const float4* wp4 = (const float4*)wp;
    const float4* wn4 = (const float4*)wn;
    for (int idx = gid; idx < n4; idx += gridDim.x * 256) {
        float4 a = wp4[idx], b = wn4[idx];
        m = fmaxf(m, fmaxf(fmaxf(fabsf(a.x), fabsf(a.y)), fmaxf(fabsf(a.z), fabsf(a.w))));
        m = fmaxf(m, fmaxf(fmaxf(fabsf(b.x), fabsf(b.y)), fmaxf(fabsf(b.z), fabsf(b.w))));
    }
    if (blockIdx.x == 0 && threadIdx.x < NOUT) {
        m = fmaxf(m, fabsf(bp[threadIdx.x]));
        m = fmaxf(m, fabsf(bn[threadIdx.x]));
    }
    #pragma unroll
    for (int off = 1; off < 64; off <<= 1)
        m = fmaxf(m, __shfl_xor(m, off, 64));
    __shared__ float sm[4];
    if ((threadIdx.x & 63) == 0) sm[threadIdx.x >> 6] = m;
    __syncthreads();
    if (threadIdx.x == 0)
        part[blockIdx.x] = fmaxf(fmaxf(sm[0], sm[1]), fmaxf(sm[2], sm[3]));
}

// ---------------------------------------------------------------------------
// Kernel 2: fused table+crossbar (R8 structure + 2-chunk loop).
// y[b,j] = C * sum_i s[b,i] * ( 2^(ep*L + lgGp) - 2^(en*L + lgGn) )
// Grid (8 jtiles, 8 bgroups, 25 z) = 1600 blocks (~6.25/CU resident, LDS
// ceiling 7). Block 256 = 64 cols (tx) x 4 batch-groups (ty); each thread
// 1 col x 8 batches. Each block: 2 sequential chunks of 16 i-rows
// (stage->sync->compute, acc in registers), then ONE epilogue ->
// atomics halved vs R8 (3.3M total, coalesced 4B each).
// LDS: 16KB table + 4.2KB Ls -> ~20.4KB.
// ---------------------------------------------------------------------------
__global__ __launch_bounds__(256) void mk_main(
    const float* __restrict__ x,  const float* __restrict__ wp,
    const float* __restrict__ wn, const float* __restrict__ bp,
    const float* __restrict__ bn, const float* __restrict__ npar,
    const float* __restrict__ pm, float* __restrict__ out)
{
    const int tid = threadIdx.x;
    const float maxw = load_maxw(pm, tid);
    const float kG = G_DIFF_F / maxw;
    const float C  = 0.5f * maxw / G_DIFF_F;    // 0.5/kG

    const int tx = tid & 63;
    const int ty = tid >> 6;
    const int j0 = blockIdx.x * 64;
    const int jp = j0 + tx;
    const int b0 = blockIdx.y * 32;

    __shared__ float4 Tb[CHUNK * 64];           // {ep, lgGp, en, lgGn}
    __shared__ float2 Ls[CHUNK][33];            // {L, s}, +1 pad

    float acc[8];
    #pragma unroll
    for (int b = 0; b < 8; ++b) acc[b] = 0.0f;

    #pragma unroll
    for (int c = 0; c < KCH; ++c) {
        const int i0 = (blockIdx.z * KCH + c) * CHUNK;
        if (c) __syncthreads();                 // protect Tb/Ls overwrite

        // --- stage table slice: 1024 (ii,jj) pairs, 4/thread, coalesced ---
        #pragma unroll
        for (int k = 0; k < 4; ++k) {
            const int p  = tid + k * 256;
            const int ii = p >> 6, jj = p & 63;
            const int i  = i0 + ii;
            float4 r = make_float4(0.f, 0.f, 0.f, 0.f);
            if (i < NROWS) {
                const float wpv = (i < NIN) ? wp[i * NOUT + j0 + jj] : bp[j0 + jj];
                const float wnv = (i < NIN) ? wn[i * NOUT + j0 + jj] : bn[j0 + jj];
                const float2 nv = *(const float2*)(&npar[i * (2 * NOUT) + 2 * (j0 + jj)]);
                r.x = dlog2(nv.x);                                  // ep
                r.y = dlog2(fmaf(kG, fmaxf(wpv, 0.0f), G_MIN_F));   // lgGp
                r.z = dlog2(nv.y);                                  // en
                r.w = dlog2(fmaf(kG, fmaxf(wnv, 0.0f), G_MIN_F));   // lgGn
            }
            Tb[p] = r;
        }

        // --- stage {log2(2|x|), sign}: 512 entries, 2/thread ---
        #pragma unroll
        for (int k = 0; k < 2; ++k) {
            const int t  = tid + k * 256;
            const int bb = t >> 4, ii = t & 15;
            const int i  = i0 + ii;
            float L = 0.0f, s = 0.0f;
            if (i < NIN) {
                const float v = x[(b0 + bb) * NIN + i];
                s = (v > 0.0f) ? 1.0f : ((v < 0.0f) ? -1.0f : 0.0f);
                L = dlog2(2.0f * fabsf(v));
            } else if (i == NIN) { L = 1.0f; s = 1.0f; }   // bias input v=1
            Ls[ii][bb] = make_float2(L, s);
        }
        __syncthreads();

        // --- inner loop: LDS-only, fully unrolled ---
        #pragma unroll
        for (int ii = 0; ii < CHUNK; ++ii) {
            const float4 tv = Tb[ii * 64 + tx];     // per-lane b128
            #pragma unroll
            for (int b = 0; b < 8; ++b) {
                const float2 ls = Ls[ii][ty * 8 + b];   // wave-uniform broadcast
                const float tp = dexp2(fmaf(tv.x, ls.x, tv.y));
                const float tn = dexp2(fmaf(tv.z, ls.x, tv.w));
                acc[b] = fmaf(ls.y, tp - tn, acc[b]);
            }
        }
    }

    #pragma unroll
    for (int b = 0; b < 8; ++b)
        unsafeAtomicAdd(&out[(b0 + ty * 8 + b) * NOUT + jp], C * acc[b]);
}

extern "C" void kernel_launch(void* const* d_in, const int* in_sizes, int n_in,
                              void* d_out, int out_size, void* d_ws, size_t ws_size,
                              hipStream_t stream) {
    const float* x    = (const float*)d_in[0];
    const float* wp   = (const float*)d_in[1];
    const float* wn   = (const float*)d_in[2];
    const float* bp   = (const float*)d_in[3];
    const float* bn   = (const float*)d_in[4];
    const float* npar = (const float*)d_in[5];
    float*        out = (float*)d_out;
    float*         pm = (float*)d_ws;           // 128 partial maxima

    // mk_max zeroes d_out (atomic target) and writes 128 partial maxima
    mk_max<<<128, 256, 0, stream>>>(wp, wn, bp, bn, pm, (float4*)out);

    dim3 grid(NOUT / 64, BATCH / 32, NZ);
    mk_main<<<grid, 256, 0, stream>>>(x, wp, wn, bp, bn, npar, pm, out);
}

// Round 16
// 42.322 us; speedup vs baseline: 1.6886x; 1.6886x over previous
//
#include <hip/hip_runtime.h>

#define NIN   784
#define NOUT  512
#define NROWS 785      // NIN + 1 (bias row)
#define BATCH 256
#define CHUNK 16       // i-rows per staged tile
#define KCH   2        // chunks per block (runtime loop, NOT unrolled)
#define NZ    25       // 25 * 32 = 800 >= 785 (pad rows contribute 0)

static constexpr float G_MIN_F  = (float)(1.0 / 983.3);
static constexpr float G_DIFF_F = (float)(1.0 / 281.3 - 1.0 / 983.3);

// device fast transcendental: v_log_f32 (log2), v_exp_f32 (2^x)
__device__ __forceinline__ float dlog2(float v) { return __builtin_amdgcn_logf(v); }
__device__ __forceinline__ float dexp2(float v) { return __builtin_amdgcn_exp2f(v); }

// 256-thread-block reduce of the 128 partial maxima (all threads return max).
__device__ __forceinline__ float load_maxw(const float* __restrict__ pm, int tid) {
    float m = pm[tid & 127];
    #pragma unroll
    for (int off = 1; off < 64; off <<= 1)
        m = fmaxf(m, __shfl_xor(m, off, 64));
    __shared__ float sm2[4];
    if ((tid & 63) == 0) sm2[tid >> 6] = m;
    __syncthreads();
    return fmaxf(fmaxf(sm2[0], sm2[1]), fmaxf(sm2[2], sm2[3]));
}

// ---------------------------------------------------------------------------
// Kernel 1: per-block partial max over |weights| (vectorized) + zero d_out.
// 128 blocks x 256 threads; 32768 float4 = exactly one per thread.
// ---------------------------------------------------------------------------
__global__ __launch_bounds__(256) void mk_max(
    const float* __restrict__ wp, const float* __restrict__ wn,
    const float* __restrict__ bp, const float* __restrict__ bn,
    float* __restrict__ part, float4* __restrict__ out4)
{
    const int gid = blockIdx.x * 256 + threadIdx.x;
    out4[gid] = make_float4(0.f, 0.f, 0.f, 0.f);

    float m = 0.0f;
    const int n4 = NIN * NOUT / 4;
    const float4* wp4 = (const float4*)wp;
    const float4* wn4 = (const float4*)wn;
    for (int idx = gid; idx < n4; idx += gridDim.x * 256) {
        float4 a = wp4[idx], b = wn4[idx];
        m = fmaxf(m, fmaxf(fmaxf(fabsf(a.x), fabsf(a.y)), fmaxf(fabsf(a.z), fabsf(a.w))));
        m = fmaxf(m, fmaxf(fmaxf(fabsf(b.x), fabsf(b.y)), fmaxf(fabsf(b.z), fabsf(b.w))));
    }
    if (blockIdx.x == 0 && threadIdx.x < NOUT) {
        m = fmaxf(m, fabsf(bp[threadIdx.x]));
        m = fmaxf(m, fabsf(bn[threadIdx.x]));
    }
    #pragma unroll
    for (int off = 1; off < 64; off <<= 1)
        m = fmaxf(m, __shfl_xor(m, off, 64));
    __shared__ float sm[4];
    if ((threadIdx.x & 63) == 0) sm[threadIdx.x >> 6] = m;
    __syncthreads();
    if (threadIdx.x == 0)
        part[blockIdx.x] = fmaxf(fmaxf(sm[0], sm[1]), fmaxf(sm[2], sm[3]));
}

// ---------------------------------------------------------------------------
// Kernel 2: fused table+crossbar — EXACT R8 structure; the only change is the
// outer KCH=2 runtime loop (unroll 1) so each block covers 2 chunks and the
// atomic epilogue runs once (3.3M atomics, half of R8).
// y[b,j] = C * sum_i s[b,i] * ( 2^(ep*L + lgGp) - 2^(en*L + lgGn) )
// Grid (8 jtiles, 8 bgroups, 25 z) = 1600 blocks; block 256 = 64 cols x 4 ty;
// each thread 1 col x 8 batches. LDS 16KB + 4.2KB.
// ---------------------------------------------------------------------------
__global__ __launch_bounds__(256) void mk_main(
    const float* __restrict__ x,  const float* __restrict__ wp,
    const float* __restrict__ wn, const float* __restrict__ bp,
    const float* __restrict__ bn, const float* __restrict__ npar,
    const float* __restrict__ pm, float* __restrict__ out)
{
    const int tid = threadIdx.x;
    const float maxw = load_maxw(pm, tid);
    const float kG = G_DIFF_F / maxw;
    const float C  = 0.5f * maxw / G_DIFF_F;    // 0.5/kG

    const int tx = tid & 63;
    const int ty = tid >> 6;
    const int j0 = blockIdx.x * 64;
    const int jp = j0 + tx;
    const int b0 = blockIdx.y * 32;

    __shared__ float4 Tb[CHUNK * 64];           // {ep, lgGp, en, lgGn}
    __shared__ float2 Ls[CHUNK][33];            // {L, s}, +1 pad

    float acc[8];
    #pragma unroll
    for (int b = 0; b < 8; ++b) acc[b] = 0.0f;

    #pragma unroll 1
    for (int c = 0; c < KCH; ++c) {             // runtime loop: keeps VGPR low
        const int i0 = (blockIdx.z * KCH + c) * CHUNK;
        if (c) __syncthreads();                 // protect Tb/Ls overwrite

        // --- stage table slice: 1024 (ii,jj) pairs, 4/thread, coalesced ---
        #pragma unroll
        for (int k = 0; k < 4; ++k) {
            const int p  = tid + k * 256;
            const int ii = p >> 6, jj = p & 63;
            const int i  = i0 + ii;
            float4 r = make_float4(0.f, 0.f, 0.f, 0.f);
            if (i < NROWS) {
                const float wpv = (i < NIN) ? wp[i * NOUT + j0 + jj] : bp[j0 + jj];
                const float wnv = (i < NIN) ? wn[i * NOUT + j0 + jj] : bn[j0 + jj];
                const float2 nv = *(const float2*)(&npar[i * (2 * NOUT) + 2 * (j0 + jj)]);
                r.x = dlog2(nv.x);                                  // ep
                r.y = dlog2(fmaf(kG, fmaxf(wpv, 0.0f), G_MIN_F));   // lgGp
                r.z = dlog2(nv.y);                                  // en
                r.w = dlog2(fmaf(kG, fmaxf(wnv, 0.0f), G_MIN_F));   // lgGn
            }
            Tb[p] = r;
        }

        // --- stage {log2(2|x|), sign}: 512 entries, 2/thread ---
        #pragma unroll
        for (int k = 0; k < 2; ++k) {
            const int t  = tid + k * 256;
            const int bb = t >> 4, ii = t & 15;
            const int i  = i0 + ii;
            float L = 0.0f, s = 0.0f;
            if (i < NIN) {
                const float v = x[(b0 + bb) * NIN + i];
                s = (v > 0.0f) ? 1.0f : ((v < 0.0f) ? -1.0f : 0.0f);
                L = dlog2(2.0f * fabsf(v));
            } else if (i == NIN) { L = 1.0f; s = 1.0f; }   // bias input v=1
            Ls[ii][bb] = make_float2(L, s);
        }
        __syncthreads();

        // --- inner loop: LDS-only, fully unrolled (one chunk working set) ---
        #pragma unroll
        for (int ii = 0; ii < CHUNK; ++ii) {
            const float4 tv = Tb[ii * 64 + tx];     // per-lane b128
            #pragma unroll
            for (int b = 0; b < 8; ++b) {
                const float2 ls = Ls[ii][ty * 8 + b];   // wave-uniform broadcast
                const float tp = dexp2(fmaf(tv.x, ls.x, tv.y));
                const float tn = dexp2(fmaf(tv.z, ls.x, tv.w));
                acc[b] = fmaf(ls.y, tp - tn, acc[b]);
            }
        }
    }

    #pragma unroll
    for (int b = 0; b < 8; ++b)
        unsafeAtomicAdd(&out[(b0 + ty * 8 + b) * NOUT + jp], C * acc[b]);
}

extern "C" void kernel_launch(void* const* d_in, const int* in_sizes, int n_in,
                              void* d_out, int out_size, void* d_ws, size_t ws_size,
                              hipStream_t stream) {
    const float* x    = (const float*)d_in[0];
    const float* wp   = (const float*)d_in[1];
    const float* wn   = (const float*)d_in[2];
    const float* bp   = (const float*)d_in[3];
    const float* bn   = (const float*)d_in[4];
    const float* npar = (const float*)d_in[5];
    float*        out = (float*)d_out;
    float*         pm = (float*)d_ws;           // 128 partial maxima

    // mk_max zeroes d_out (atomic target) and writes 128 partial maxima
    mk_max<<<128, 256, 0, stream>>>(wp, wn, bp, bn, pm, (float4*)out);

    dim3 grid(NOUT / 64, BATCH / 32, NZ);
    mk_main<<<grid, 256, 0, stream>>>(x, wp, wn, bp, bn, npar, pm, out);
}